// Round 3
// baseline (871.684 us; speedup 1.0000x reference)
//
#include <hip/hip_runtime.h>

// LSALayer fused: windowed (4x4 patch, 16-token) self-attention, C=256.
// Register-resident dataflow, ZERO LDS, zero barriers.
// Round 2 (re-run; prior attempt hit an infra failure, no signal):
// ONE window per wave (halved register state -> ~2x occupancy),
// split-accumulator MFMA chains, and a fully-transposed epilogue so output
// stores are contiguous float4 per lane.
//
// Layout invariant (from swapped GEMM1): lane (l15,quad), tile nt, reg r holds
//   qf[nt][r] = bf16( Q[token=l15][c = nt*16 + quad*4 + r] + bq[c] )
// which is simultaneously the A-frag and B-frag layout of mfma_16x16x16_bf16.
//  - S = Q Q^T straight from regs; softmax reduces over quads (shfl_xor 16/32).
//    paf[j] = P[l15][quad*4+j]  == A-frag of P == B-frag of P^T (same bits!).
//  - out^T = (Q Wo^T)^T P^T: Y^T-frag (via identity-MFMA transpose) as A,
//    paf as B -> lane holds out[token=l15][ch=nt*16+quad*4+r] -> float4 store.

typedef __attribute__((ext_vector_type(8))) short short8;   // 8 bf16
typedef __attribute__((ext_vector_type(4))) short short4v;  // 4 bf16
typedef __attribute__((ext_vector_type(4))) float floatx4;  // MFMA C/D

#define MFMA32(a, b, c) __builtin_amdgcn_mfma_f32_16x16x32_bf16(a, b, c, 0, 0, 0)
#define MFMA16(a, b, c) __builtin_amdgcn_mfma_f32_16x16x16bf16_1k(a, b, c, 0, 0, 0)

static __device__ inline short f2bf(float f) {
    unsigned u = __float_as_uint(f);
    u = (u + 0x7FFFu + ((u >> 16) & 1u)) >> 16;  // RNE
    return (short)u;
}
static __device__ inline floatx4 zf4() {
    floatx4 v;
#pragma unroll
    for (int k = 0; k < 4; ++k) v[k] = 0.0f;
    return v;
}
static __device__ inline short8 cvt8(float4 v0, float4 v1) {
    short8 a;
    a[0] = f2bf(v0.x); a[1] = f2bf(v0.y); a[2] = f2bf(v0.z); a[3] = f2bf(v0.w);
    a[4] = f2bf(v1.x); a[5] = f2bf(v1.y); a[6] = f2bf(v1.z); a[7] = f2bf(v1.w);
    return a;
}
static __device__ inline short4v pack4(floatx4 a) {
    short4v r;
    r[0] = f2bf(a[0]); r[1] = f2bf(a[1]); r[2] = f2bf(a[2]); r[3] = f2bf(a[3]);
    return r;
}
static __device__ inline short4v pack4sb(floatx4 a, floatx4 b, float4 c) {
    short4v r;
    r[0] = f2bf(a[0] + b[0] + c.x); r[1] = f2bf(a[1] + b[1] + c.y);
    r[2] = f2bf(a[2] + b[2] + c.z); r[3] = f2bf(a[3] + b[3] + c.w);
    return r;
}

// Wq: row-major bf16 (GEMM1 A-frag does 16B loads of 8 contiguous k).
// Wo: permuted so one 16B load serves TWO K=16 fragments:
//   src k = kk*16 + q4*4 + r  ->  dst = (kk>>1)*32 + q4*8 + (kk&1)*4 + r
__global__ void convert_weights(const float* __restrict__ Wq,
                                const float* __restrict__ Wo,
                                short* __restrict__ wbf) {
    int idx = blockIdx.x * 256 + threadIdx.x;  // 0..65535
    int n = idx >> 8, k = idx & 255;
    wbf[idx] = f2bf(Wq[idx]);
    int kk = k >> 4, q4 = (k >> 2) & 3, r = k & 3;
    int pk = (kk >> 1) * 32 + q4 * 8 + (kk & 1) * 4 + r;
    wbf[65536 + n * 256 + pk] = f2bf(Wo[idx]);
}

// Block = 256 threads = 4 waves; each wave owns ONE window.
// Grid = 4096 blocks -> 16384 windows. No LDS, no barriers.
__global__ __launch_bounds__(256, 4) void lsa_fused(
    const float* __restrict__ x, const short* __restrict__ wbf,
    const float* __restrict__ bq, const float* __restrict__ bo,
    float* __restrict__ out) {
    const int tid  = threadIdx.x;
    const int wv   = tid >> 6;
    const int lane = tid & 63;
    const int l15  = lane & 15;
    const int quad = lane >> 4;

    const int wid = blockIdx.x * 4 + wv;      // 0..16383
    const int pi = l15 >> 2, pj = l15 & 3;    // token l15 -> pixel in 4x4 patch
    const int b = wid >> 12, hp = (wid >> 6) & 63, wp = wid & 63;
    const float* xrow = x + ((size_t)b << 24) + ((size_t)((hp << 2) + pi) << 16)
                          + ((size_t)((wp << 2) + pj) << 8);

    // ---- stage X (HBM) into bf16 B-frags: lane holds X[l15][kk*32+quad*8 ..+8]
    short8 xf[8];
#pragma unroll
    for (int kk = 0; kk < 8; ++kk) {
        const float* p = xrow + kk * 32 + quad * 8;
        float4 v0 = *(const float4*)p;
        float4 v1 = *(const float4*)(p + 4);
        xf[kk] = cvt8(v0, v1);
    }

    // ---- GEMM1 (swapped): mfma(Wq_frag, X_frag) -> Q transposed in regs.
    // Two independent 4-deep chains (even/odd K-tiles), VALU-merged.
    short4v qf[16];
#pragma unroll 2
    for (int nt = 0; nt < 16; ++nt) {
        floatx4 a0 = zf4(), a1 = zf4();
        const short* wq = wbf + (nt * 16 + l15) * 256 + quad * 8;
#pragma unroll
        for (int kk = 0; kk < 4; ++kk) {
            short8 w0 = *(const short8*)(wq + kk * 64);
            short8 w1 = *(const short8*)(wq + kk * 64 + 32);
            a0 = MFMA32(w0, xf[2 * kk], a0);
            a1 = MFMA32(w1, xf[2 * kk + 1], a1);
        }
        float4 b4 = *(const float4*)(bq + nt * 16 + quad * 4);
        qf[nt] = pack4sb(a0, a1, b4);
    }

    // ---- S = Q Q^T from registers (16x16x16, A==B), two chains.
    // s[r] = S[quad*4+r][l15] == (symmetry) S[l15][quad*4+r].
    floatx4 sa = zf4(), sb = zf4();
#pragma unroll
    for (int h = 0; h < 8; ++h) {
        sa = MFMA16(qf[2 * h], qf[2 * h], sa);
        sb = MFMA16(qf[2 * h + 1], qf[2 * h + 1], sb);
    }
    floatx4 s = sa + sb;

    // ---- softmax over row l15: in-lane over r, then across quads.
    // paf[r] = P[l15][quad*4+r] == A-frag of P == B-frag of P^T.
    float m = fmaxf(fmaxf(s[0], s[1]), fmaxf(s[2], s[3]));
    m = fmaxf(m, __shfl_xor(m, 16, 64));
    m = fmaxf(m, __shfl_xor(m, 32, 64));
    float e0 = __expf(s[0] - m), e1 = __expf(s[1] - m);
    float e2 = __expf(s[2] - m), e3 = __expf(s[3] - m);
    float sum = (e0 + e1) + (e2 + e3);
    sum += __shfl_xor(sum, 16, 64);
    sum += __shfl_xor(sum, 32, 64);
    float inv = 1.0f / sum;
    short4v paf;
    paf[0] = f2bf(e0 * inv); paf[1] = f2bf(e1 * inv);
    paf[2] = f2bf(e2 * inv); paf[3] = f2bf(e3 * inv);

    // identity B-frag (bf16 1.0 = 0x3F80) for the in-register transpose mfma
    short4v idf;
#pragma unroll
    for (int j = 0; j < 4; ++j) idf[j] = (l15 == quad * 4 + j) ? (short)0x3F80 : (short)0;

    float* op = out + (size_t)wid * 4096 + l15 * 256;  // token row base

    // ---- per 16-ch tile: Y = Q Wo^T (reg-Q as B, two chains), transpose Y via
    // identity mfma, out^T tile = Y^T-frag * paf, add bo, contiguous f4 store.
#pragma unroll 2
    for (int nt = 0; nt < 16; ++nt) {
        floatx4 y0 = zf4(), y1 = zf4();
        const short* wo = wbf + 65536 + (nt * 16 + l15) * 256 + quad * 8;
#pragma unroll
        for (int kk2 = 0; kk2 < 8; ++kk2) {
            short8 wf = *(const short8*)(wo + kk2 * 32);
            short4v wlo, whi;
            wlo[0] = wf[0]; wlo[1] = wf[1]; wlo[2] = wf[2]; wlo[3] = wf[3];
            whi[0] = wf[4]; whi[1] = wf[5]; whi[2] = wf[6]; whi[3] = wf[7];
            y0 = MFMA16(wlo, qf[2 * kk2], y0);
            y1 = MFMA16(whi, qf[2 * kk2 + 1], y1);
        }
        floatx4 y = y0 + y1;
        // y[r] = Y[token l15][nt*16+quad*4+r]  --(identity mfma)-->
        // t[r] = Y[token quad*4+r][nt*16+l15]  == A-frag of Y^T (m=ch, k=token)
        floatx4 t = MFMA16(pack4(y), idf, zf4());
        // out^T = Y^T * P^T: D[m=ch][n=token]; lane holds
        // out[token=l15][ch = nt*16 + quad*4 + r] -> contiguous float4.
        floatx4 oT = MFMA16(pack4(t), paf, zf4());
        float4 bo4 = *(const float4*)(bo + nt * 16 + quad * 4);
        float4 st;
        st.x = oT[0] + bo4.x; st.y = oT[1] + bo4.y;
        st.z = oT[2] + bo4.z; st.w = oT[3] + bo4.w;
        *(float4*)(op + nt * 16 + quad * 4) = st;
    }
}

extern "C" void kernel_launch(void* const* d_in, const int* in_sizes, int n_in,
                              void* d_out, int out_size, void* d_ws, size_t ws_size,
                              hipStream_t stream) {
    const float* x  = (const float*)d_in[0];
    const float* Wq = (const float*)d_in[1];
    const float* bq = (const float*)d_in[2];
    const float* Wo = (const float*)d_in[3];
    const float* bo = (const float*)d_in[4];
    float* out = (float*)d_out;
    short* wbf = (short*)d_ws;  // [0,65536): Wq bf16; [65536,131072): Wo bf16 (permuted)

    hipLaunchKernelGGL(convert_weights, dim3(256), dim3(256), 0, stream, Wq, Wo, wbf);
    hipLaunchKernelGGL(lsa_fused, dim3(4096), dim3(256), 0, stream,
                       x, wbf, bq, bo, out);
}

// Round 4
// 698.234 us; speedup vs baseline: 1.2484x; 1.2484x over previous
//
#include <hip/hip_runtime.h>

// LSALayer fused: windowed (4x4 patch, 16-token) self-attention, C=256.
// Round 4: LDS-staged weights, shared per workgroup.
//   Diagnosis: rounds 0-3 are bound by per-wave L2/L3 weight-fragment load
//   latency (round 3: 2x loads/window -> 1.72x slower despite higher occ).
//   Fix: block of 4 waves (8 windows) stages Wq+Wo ONCE via global_load_lds
//   (16 KB chunks, double-buffered, 1 barrier/chunk) -> 4x less weight
//   traffic, MFMA operands from LDS (XOR-swizzled, 2-way conflict = free).
//   global_load_lds writes linearly, so the swizzle is pre-applied to the
//   GLOBAL layout in convert_weights (rule: both-sides-or-neither).
//
// Dataflow per wave (2 windows, proven in rounds 1/3):
//   qf[w][nt][r] = bf16( Q[token=l15][c=nt*16+quad*4+r] + bq )   (swapped G1)
//   S = Q Q^T from regs; softmax over quads; paf = A-frag of P = B-frag of P^T.
//   out^T = (Q Wo^T)^T P^T via identity-MFMA transpose -> contiguous f4 stores.

typedef __attribute__((ext_vector_type(8))) short short8;   // 8 bf16
typedef __attribute__((ext_vector_type(4))) short short4v;  // 4 bf16
typedef __attribute__((ext_vector_type(4))) float floatx4;  // MFMA C/D

#define MFMA32(a, b, c) __builtin_amdgcn_mfma_f32_16x16x32_bf16(a, b, c, 0, 0, 0)
#define MFMA16(a, b, c) __builtin_amdgcn_mfma_f32_16x16x16bf16_1k(a, b, c, 0, 0, 0)

typedef __attribute__((address_space(1))) const unsigned int GU32;
typedef __attribute__((address_space(3))) unsigned int LU32;

static __device__ inline short f2bf(float f) {
    unsigned u = __float_as_uint(f);
    u = (u + 0x7FFFu + ((u >> 16) & 1u)) >> 16;  // RNE
    return (short)u;
}
static __device__ inline floatx4 zf4() {
    floatx4 v;
#pragma unroll
    for (int k = 0; k < 4; ++k) v[k] = 0.0f;
    return v;
}
static __device__ inline short8 cvt8(float4 v0, float4 v1) {
    short8 a;
    a[0] = f2bf(v0.x); a[1] = f2bf(v0.y); a[2] = f2bf(v0.z); a[3] = f2bf(v0.w);
    a[4] = f2bf(v1.x); a[5] = f2bf(v1.y); a[6] = f2bf(v1.z); a[7] = f2bf(v1.w);
    return a;
}
static __device__ inline short4v pack4(floatx4 a) {
    short4v r;
    r[0] = f2bf(a[0]); r[1] = f2bf(a[1]); r[2] = f2bf(a[2]); r[3] = f2bf(a[3]);
    return r;
}
static __device__ inline short4v pack4b(floatx4 a, float4 c) {
    short4v r;
    r[0] = f2bf(a[0] + c.x); r[1] = f2bf(a[1] + c.y);
    r[2] = f2bf(a[2] + c.z); r[3] = f2bf(a[3] + c.w);
    return r;
}

// Weight image in d_ws (256 KB), pre-swizzled for linear global_load_lds:
//  Wq region [0,131072) B: chunk c=row>>5 (16 KB each), within chunk
//    byte = ((row&31)*512 + 2*k) ^ (((row&7))<<4)
//  Wo region [131072,262144) B: k first permuted within row so one 16B read
//    yields TWO K=16 A-frags:  pk = (kk>>1)*32 + q4*8 + (kk&1)*4 + r
//    then same chunk+swizzle with k -> pk.
__global__ void convert_weights(const float* __restrict__ Wq,
                                const float* __restrict__ Wo,
                                short* __restrict__ wbf) {
    int idx = blockIdx.x * 256 + threadIdx.x;  // 0..65535
    int row = idx >> 8, k = idx & 255;
    int rr = row & 31, c = row >> 5;
    int swz = (rr & 7) << 4;

    int offq = (rr * 512 + k * 2) ^ swz;
    wbf[(c * 16384 + offq) >> 1] = f2bf(Wq[idx]);

    int kk = k >> 4, q4 = (k >> 2) & 3, r = k & 3;
    int pk = (kk >> 1) * 32 + q4 * 8 + (kk & 1) * 4 + r;
    int offo = (rr * 512 + pk * 2) ^ swz;
    wbf[(131072 + c * 16384 + offo) >> 1] = f2bf(Wo[idx]);
}

// Block = 256 threads = 4 waves; each wave owns TWO windows (8 windows/block).
// Grid = 2048 blocks -> 16384 windows.
__global__ __launch_bounds__(256, 3) void lsa_fused(
    const float* __restrict__ x, const short* __restrict__ wbf,
    const float* __restrict__ bq, const float* __restrict__ bo,
    float* __restrict__ out) {
    __shared__ __align__(16) short lds[2][8192];  // 2 x 16 KB chunk buffers

    const int tid  = threadIdx.x;
    const int wv   = tid >> 6;
    const int lane = tid & 63;
    const int l15  = lane & 15;
    const int quad = lane >> 4;
    const int swz  = (l15 & 7) << 4;

    // stage one 16 KB weight chunk g (0..15) into lds[b]; linear, lane-contig.
#define STAGE(b, g)                                                            \
    do {                                                                       \
        const short* _src = wbf + (size_t)(g) * 8192 + tid * 8;                \
        short* _dst = &lds[b][tid * 8];                                        \
        _Pragma("unroll") for (int _i = 0; _i < 4; ++_i)                       \
            __builtin_amdgcn_global_load_lds((GU32*)(_src + _i * 2048),        \
                                             (LU32*)(_dst + _i * 2048),        \
                                             16, 0, 0);                        \
    } while (0)

    const int wid0 = (blockIdx.x * 4 + wv) * 2;
    const int pi = l15 >> 2, pj = l15 & 3;  // token l15 -> pixel in 4x4 patch

    const float* xrow[2];
#pragma unroll
    for (int w = 0; w < 2; ++w) {
        int wid = wid0 + w;
        int b = wid >> 12, hp = (wid >> 6) & 63, wp = wid & 63;
        xrow[w] = x + ((size_t)b << 24) + ((size_t)((hp << 2) + pi) << 16)
                    + ((size_t)((wp << 2) + pj) << 8);
    }

    // issue chunk-0 staging, then X loads (all drained by the first barrier)
    STAGE(0, 0);

    short8 xf[2][8];  // lane holds X[token=l15][kk*32 + quad*8 ..+8]
#pragma unroll
    for (int w = 0; w < 2; ++w)
#pragma unroll
        for (int kk = 0; kk < 8; ++kk) {
            const float* p = xrow[w] + kk * 32 + quad * 8;
            float4 v0 = *(const float4*)p;
            float4 v1 = *(const float4*)(p + 4);
            xf[w][kk] = cvt8(v0, v1);
        }

    __syncthreads();  // drains vmcnt(0): chunk 0 + X loads

    // ---- GEMM1: 8 chunks x 2 nt-tiles; stage chunk c+1 while computing c.
    short4v qf[2][16];
    const int lbase = l15 * 512 + quad * 16;
#pragma unroll 1
    for (int c = 0; c < 8; ++c) {
        STAGE((c + 1) & 1, c + 1);  // c=7 stages chunk 8 = Wo chunk 0
        const char* Lb = (const char*)&lds[c & 1][0];
#pragma unroll
        for (int h = 0; h < 2; ++h) {
            const int nt = c * 2 + h;
            floatx4 a0 = zf4(), a1 = zf4();
            const int base = lbase + h * 8192;
#pragma unroll
            for (int kk = 0; kk < 8; ++kk) {
                short8 wf = *(const short8*)(Lb + ((base + kk * 64) ^ swz));
                a0 = MFMA32(wf, xf[0][kk], a0);
                a1 = MFMA32(wf, xf[1][kk], a1);
            }
            float4 b4 = *(const float4*)(bq + nt * 16 + quad * 4);
            qf[0][nt] = pack4b(a0, b4);
            qf[1][nt] = pack4b(a1, b4);
        }
        __syncthreads();
    }

    // ---- S = Q Q^T from registers (16x16x16, A==B), 2 chains per window.
    floatx4 s0a = zf4(), s0b = zf4(), s1a = zf4(), s1b = zf4();
#pragma unroll
    for (int h = 0; h < 8; ++h) {
        s0a = MFMA16(qf[0][2 * h], qf[0][2 * h], s0a);
        s0b = MFMA16(qf[0][2 * h + 1], qf[0][2 * h + 1], s0b);
        s1a = MFMA16(qf[1][2 * h], qf[1][2 * h], s1a);
        s1b = MFMA16(qf[1][2 * h + 1], qf[1][2 * h + 1], s1b);
    }

    // ---- softmax over row l15 (in-lane over r, then across quads).
    short4v paf[2];
#pragma unroll
    for (int w = 0; w < 2; ++w) {
        floatx4 s = w ? (s1a + s1b) : (s0a + s0b);
        float m = fmaxf(fmaxf(s[0], s[1]), fmaxf(s[2], s[3]));
        m = fmaxf(m, __shfl_xor(m, 16, 64));
        m = fmaxf(m, __shfl_xor(m, 32, 64));
        float e0 = __expf(s[0] - m), e1 = __expf(s[1] - m);
        float e2 = __expf(s[2] - m), e3 = __expf(s[3] - m);
        float sum = (e0 + e1) + (e2 + e3);
        sum += __shfl_xor(sum, 16, 64);
        sum += __shfl_xor(sum, 32, 64);
        float inv = 1.0f / sum;
        short4v pf;
        pf[0] = f2bf(e0 * inv); pf[1] = f2bf(e1 * inv);
        pf[2] = f2bf(e2 * inv); pf[3] = f2bf(e3 * inv);
        paf[w] = pf;
    }

    // identity B-frag (bf16 1.0 = 0x3F80) for the in-register transpose mfma
    short4v idf;
#pragma unroll
    for (int j = 0; j < 4; ++j) idf[j] = (l15 == quad * 4 + j) ? (short)0x3F80 : (short)0;

    float* op0 = out + (size_t)wid0 * 4096 + l15 * 256;  // token row base
    float* op1 = op0 + 4096;

    // ---- GEMM2 + PV: 8 chunks x 2 nt-tiles from LDS (Wo, permuted layout).
    // Y = Q Wo^T (reg-Q as B, 2 chains/window); transpose Y via identity mfma;
    // out^T tile = Y^T-frag * paf -> contiguous float4 stores.
#pragma unroll 1
    for (int c = 0; c < 8; ++c) {
        if (c < 7) STAGE((c + 1) & 1, 9 + c);
        const char* Lb = (const char*)&lds[c & 1][0];
#pragma unroll
        for (int h = 0; h < 2; ++h) {
            const int nt = c * 2 + h;
            floatx4 y00 = zf4(), y01 = zf4(), y10 = zf4(), y11 = zf4();
            const int base = lbase + h * 8192;
#pragma unroll
            for (int kk2 = 0; kk2 < 8; ++kk2) {
                short8 wf = *(const short8*)(Lb + ((base + kk2 * 64) ^ swz));
                short4v wlo, whi;
                wlo[0] = wf[0]; wlo[1] = wf[1]; wlo[2] = wf[2]; wlo[3] = wf[3];
                whi[0] = wf[4]; whi[1] = wf[5]; whi[2] = wf[6]; whi[3] = wf[7];
                y00 = MFMA16(wlo, qf[0][2 * kk2], y00);
                y10 = MFMA16(wlo, qf[1][2 * kk2], y10);
                y01 = MFMA16(whi, qf[0][2 * kk2 + 1], y01);
                y11 = MFMA16(whi, qf[1][2 * kk2 + 1], y11);
            }
            // y[r] = Y[token l15][nt*16+quad*4+r] --(identity)-->
            // t[r] = Y[token quad*4+r][nt*16+l15] == A-frag of Y^T
            floatx4 t0 = MFMA16(pack4(y00 + y01), idf, zf4());
            floatx4 t1 = MFMA16(pack4(y10 + y11), idf, zf4());
            floatx4 o0 = MFMA16(pack4(t0), paf[0], zf4());
            floatx4 o1 = MFMA16(pack4(t1), paf[1], zf4());
            float4 bo4 = *(const float4*)(bo + nt * 16 + quad * 4);
            float4 r0, r1;
            r0.x = o0[0] + bo4.x; r0.y = o0[1] + bo4.y;
            r0.z = o0[2] + bo4.z; r0.w = o0[3] + bo4.w;
            r1.x = o1[0] + bo4.x; r1.y = o1[1] + bo4.y;
            r1.z = o1[2] + bo4.z; r1.w = o1[3] + bo4.w;
            *(float4*)(op0 + nt * 16 + quad * 4) = r0;
            *(float4*)(op1 + nt * 16 + quad * 4) = r1;
        }
        __syncthreads();
    }
#undef STAGE
}

extern "C" void kernel_launch(void* const* d_in, const int* in_sizes, int n_in,
                              void* d_out, int out_size, void* d_ws, size_t ws_size,
                              hipStream_t stream) {
    const float* x  = (const float*)d_in[0];
    const float* Wq = (const float*)d_in[1];
    const float* bq = (const float*)d_in[2];
    const float* Wo = (const float*)d_in[3];
    const float* bo = (const float*)d_in[4];
    float* out = (float*)d_out;
    short* wbf = (short*)d_ws;  // 256 KB pre-swizzled weight image (see above)

    hipLaunchKernelGGL(convert_weights, dim3(256), dim3(256), 0, stream, Wq, Wo, wbf);
    hipLaunchKernelGGL(lsa_fused, dim3(2048), dim3(256), 0, stream,
                       x, wbf, bq, bo, out);
}

// Round 5
// 660.141 us; speedup vs baseline: 1.3205x; 1.0577x over previous
//
#include <hip/hip_runtime.h>

// LSALayer fused: windowed (4x4 patch, 16-token) self-attention, C=256.
// Register-resident dataflow, ZERO LDS, zero barriers.
// Round 5: identical dataflow to round 1; ONLY change is __launch_bounds__
// (256,3)->(256,2). Diagnosis: R1's "(,3)" demanded 3 waves/SIMD, capping the
// allocator at 84 arch VGPRs while the dataflow needs ~128 persistent regs
// (xf[2][8] + qf[2][16]) -> compiler spilled to scratch. Evidence:
// WRITE_SIZE 399 MB = 268 MB output + 131 MB = 16 KB/wave = sizeof(xf) -- the
// spill stream reaching HBM. Every fragment use round-trips scratch at
// L2/HBM latency, which is why all pipes sit <30% busy at any occupancy.
// Fix: allow 256 unified regs (2 waves/SIMD), zero spills.
//
// Layout invariant (swapped GEMM1): lane (l15,quad), tile nt, reg r holds
//   qf[w][nt][r] = bf16( Q[token=l15][c = nt*16 + quad*4 + r] + bq[c] )
// which is simultaneously the A-frag and B-frag layout of mfma_16x16x16_bf16.
//  - S = Q Q^T straight from regs; softmax reduces over quads (shfl_xor 16/32).
//    paf[j] = P[l15][quad*4+j]  == A-frag of P == B-frag of P^T (same bits!).
//  - out^T = (Q Wo^T)^T P^T: Y^T-frag (via identity-MFMA transpose) as A,
//    paf as B -> lane holds out[token=l15][ch=nt*16+quad*4+r] -> float4 store.

typedef __attribute__((ext_vector_type(8))) short short8;   // 8 bf16
typedef __attribute__((ext_vector_type(4))) short short4v;  // 4 bf16
typedef __attribute__((ext_vector_type(4))) float floatx4;  // MFMA C/D

#define MFMA32(a, b, c) __builtin_amdgcn_mfma_f32_16x16x32_bf16(a, b, c, 0, 0, 0)
#define MFMA16(a, b, c) __builtin_amdgcn_mfma_f32_16x16x16bf16_1k(a, b, c, 0, 0, 0)

static __device__ inline short f2bf(float f) {
    unsigned u = __float_as_uint(f);
    u = (u + 0x7FFFu + ((u >> 16) & 1u)) >> 16;  // RNE
    return (short)u;
}
static __device__ inline floatx4 zf4() {
    floatx4 v;
#pragma unroll
    for (int k = 0; k < 4; ++k) v[k] = 0.0f;
    return v;
}
static __device__ inline short8 cvt8(float4 v0, float4 v1) {
    short8 a;
    a[0] = f2bf(v0.x); a[1] = f2bf(v0.y); a[2] = f2bf(v0.z); a[3] = f2bf(v0.w);
    a[4] = f2bf(v1.x); a[5] = f2bf(v1.y); a[6] = f2bf(v1.z); a[7] = f2bf(v1.w);
    return a;
}
static __device__ inline short4v pack4(floatx4 a) {
    short4v r;
    r[0] = f2bf(a[0]); r[1] = f2bf(a[1]); r[2] = f2bf(a[2]); r[3] = f2bf(a[3]);
    return r;
}
static __device__ inline short4v pack4b(floatx4 a, float4 b) {
    short4v r;
    r[0] = f2bf(a[0] + b.x); r[1] = f2bf(a[1] + b.y);
    r[2] = f2bf(a[2] + b.z); r[3] = f2bf(a[3] + b.w);
    return r;
}

// Wq: row-major bf16 (GEMM1 A-frag does 16B loads of 8 contiguous k).
// Wo: permuted so one 16B load serves TWO K=16 fragments:
//   src k = kk*16 + q4*4 + r  ->  dst = (kk>>1)*32 + q4*8 + (kk&1)*4 + r
__global__ void convert_weights(const float* __restrict__ Wq,
                                const float* __restrict__ Wo,
                                short* __restrict__ wbf) {
    int idx = blockIdx.x * 256 + threadIdx.x;  // 0..65535
    int n = idx >> 8, k = idx & 255;
    wbf[idx] = f2bf(Wq[idx]);
    int kk = k >> 4, q4 = (k >> 2) & 3, r = k & 3;
    int pk = (kk >> 1) * 32 + q4 * 8 + (kk & 1) * 4 + r;
    wbf[65536 + n * 256 + pk] = f2bf(Wo[idx]);
}

// Block = 256 threads = 4 waves; each wave owns TWO windows (shared B-frags).
// Grid = 2048 blocks -> 16384 windows. No LDS, no barriers.
__global__ __launch_bounds__(256, 2) void lsa_fused(
    const float* __restrict__ x, const short* __restrict__ wbf,
    const float* __restrict__ bq, const float* __restrict__ bo,
    float* __restrict__ out) {
    const int tid  = threadIdx.x;
    const int wv   = tid >> 6;
    const int lane = tid & 63;
    const int l15  = lane & 15;
    const int quad = lane >> 4;

    const int wid0 = (blockIdx.x * 4 + wv) * 2;
    const int pi = l15 >> 2, pj = l15 & 3;  // token l15 -> pixel in 4x4 patch

    const float* xrow[2];
#pragma unroll
    for (int w = 0; w < 2; ++w) {
        int wid = wid0 + w;
        int b = wid >> 12, hp = (wid >> 6) & 63, wp = wid & 63;
        xrow[w] = x + ((size_t)b << 24) + ((size_t)((hp << 2) + pi) << 16)
                    + ((size_t)((wp << 2) + pj) << 8);
    }

    // ---- stage X (HBM) into bf16 B-frags: lane holds X[l15][kk*32+quad*8 ..+8]
    short8 xf[2][8];
#pragma unroll
    for (int w = 0; w < 2; ++w)
#pragma unroll
        for (int kk = 0; kk < 8; ++kk) {
            const float* p = xrow[w] + kk * 32 + quad * 8;
            float4 v0 = *(const float4*)p;
            float4 v1 = *(const float4*)(p + 4);
            xf[w][kk] = cvt8(v0, v1);
        }

    // ---- GEMM1 (swapped): acc = mfma(Wq_frag, X_frag) -> Q transposed in regs.
    short4v qf[2][16];
#pragma unroll 2
    for (int nt = 0; nt < 16; ++nt) {
        floatx4 a0 = zf4(), a1 = zf4();
        const short* wq = wbf + (nt * 16 + l15) * 256 + quad * 8;
#pragma unroll
        for (int kk = 0; kk < 8; ++kk) {
            short8 wf = *(const short8*)(wq + kk * 32);
            a0 = MFMA32(wf, xf[0][kk], a0);
            a1 = MFMA32(wf, xf[1][kk], a1);
        }
        float4 b4 = *(const float4*)(bq + nt * 16 + quad * 4);
        qf[0][nt] = pack4b(a0, b4);
        qf[1][nt] = pack4b(a1, b4);
    }

    // ---- S = Q Q^T from registers (16x16x16, A==B), two chains per window.
    floatx4 s0a = zf4(), s0b = zf4(), s1a = zf4(), s1b = zf4();
#pragma unroll
    for (int h = 0; h < 8; ++h) {
        s0a = MFMA16(qf[0][2 * h], qf[0][2 * h], s0a);
        s0b = MFMA16(qf[0][2 * h + 1], qf[0][2 * h + 1], s0b);
        s1a = MFMA16(qf[1][2 * h], qf[1][2 * h], s1a);
        s1b = MFMA16(qf[1][2 * h + 1], qf[1][2 * h + 1], s1b);
    }

    // ---- softmax over row l15: in-lane over r, then across quads.
    // paf[r] = P[l15][quad*4+r] == A-frag of P == B-frag of P^T.
    short4v paf[2];
#pragma unroll
    for (int w = 0; w < 2; ++w) {
        floatx4 s = w ? (s1a + s1b) : (s0a + s0b);
        float m = fmaxf(fmaxf(s[0], s[1]), fmaxf(s[2], s[3]));
        m = fmaxf(m, __shfl_xor(m, 16, 64));
        m = fmaxf(m, __shfl_xor(m, 32, 64));
        float e0 = __expf(s[0] - m), e1 = __expf(s[1] - m);
        float e2 = __expf(s[2] - m), e3 = __expf(s[3] - m);
        float sum = (e0 + e1) + (e2 + e3);
        sum += __shfl_xor(sum, 16, 64);
        sum += __shfl_xor(sum, 32, 64);
        float inv = 1.0f / sum;
        short4v pf;
        pf[0] = f2bf(e0 * inv); pf[1] = f2bf(e1 * inv);
        pf[2] = f2bf(e2 * inv); pf[3] = f2bf(e3 * inv);
        paf[w] = pf;
    }

    // identity B-frag (bf16 1.0 = 0x3F80) for the in-register transpose mfma
    short4v idf;
#pragma unroll
    for (int j = 0; j < 4; ++j) idf[j] = (l15 == quad * 4 + j) ? (short)0x3F80 : (short)0;

    float* op0 = out + (size_t)wid0 * 4096 + l15 * 256;  // token row base
    float* op1 = op0 + 4096;

    // ---- per 16-ch tile: Y = Q Wo^T (reg-Q as B, two chains per window),
    // transpose Y via identity mfma, out^T tile = Y^T-frag * paf, add bo,
    // contiguous float4 store.
#pragma unroll 2
    for (int nt = 0; nt < 16; ++nt) {
        floatx4 y00 = zf4(), y01 = zf4(), y10 = zf4(), y11 = zf4();
        const short* wo = wbf + 65536 + (nt * 16 + l15) * 256 + quad * 8;
#pragma unroll
        for (int kk2 = 0; kk2 < 8; ++kk2) {
            short8 wf = *(const short8*)(wo + kk2 * 32);
            short4v wlo, whi;
            wlo[0] = wf[0]; wlo[1] = wf[1]; wlo[2] = wf[2]; wlo[3] = wf[3];
            whi[0] = wf[4]; whi[1] = wf[5]; whi[2] = wf[6]; whi[3] = wf[7];
            y00 = MFMA16(wlo, qf[0][2 * kk2], y00);
            y10 = MFMA16(wlo, qf[1][2 * kk2], y10);
            y01 = MFMA16(whi, qf[0][2 * kk2 + 1], y01);
            y11 = MFMA16(whi, qf[1][2 * kk2 + 1], y11);
        }
        // y[r] = Y[token l15][nt*16+quad*4+r]  --(identity mfma)-->
        // t[r] = Y[token quad*4+r][nt*16+l15]  == A-frag of Y^T (m=ch, k=token)
        floatx4 t0 = MFMA16(pack4(y00 + y01), idf, zf4());
        floatx4 t1 = MFMA16(pack4(y10 + y11), idf, zf4());
        // out^T = Y^T * P^T: lane holds out[token=l15][ch=nt*16+quad*4+r]
        floatx4 o0 = MFMA16(pack4(t0), paf[0], zf4());
        floatx4 o1 = MFMA16(pack4(t1), paf[1], zf4());
        float4 bo4 = *(const float4*)(bo + nt * 16 + quad * 4);
        float4 r0, r1;
        r0.x = o0[0] + bo4.x; r0.y = o0[1] + bo4.y;
        r0.z = o0[2] + bo4.z; r0.w = o0[3] + bo4.w;
        r1.x = o1[0] + bo4.x; r1.y = o1[1] + bo4.y;
        r1.z = o1[2] + bo4.z; r1.w = o1[3] + bo4.w;
        *(float4*)(op0 + nt * 16 + quad * 4) = r0;
        *(float4*)(op1 + nt * 16 + quad * 4) = r1;
    }
}

extern "C" void kernel_launch(void* const* d_in, const int* in_sizes, int n_in,
                              void* d_out, int out_size, void* d_ws, size_t ws_size,
                              hipStream_t stream) {
    const float* x  = (const float*)d_in[0];
    const float* Wq = (const float*)d_in[1];
    const float* bq = (const float*)d_in[2];
    const float* Wo = (const float*)d_in[3];
    const float* bo = (const float*)d_in[4];
    float* out = (float*)d_out;
    short* wbf = (short*)d_ws;  // [0,65536): Wq bf16; [65536,131072): Wo bf16 (permuted)

    hipLaunchKernelGGL(convert_weights, dim3(256), dim3(256), 0, stream, Wq, Wo, wbf);
    hipLaunchKernelGGL(lsa_fused, dim3(2048), dim3(256), 0, stream,
                       x, wbf, bq, bo, out);
}